// Round 10
// baseline (7337.370 us; speedup 1.0000x reference)
//
#include <hip/hip_runtime.h>
#include <stdint.h>

#define HDIM  512
#define NCLS  1000

typedef _Float16 f16x8 __attribute__((ext_vector_type(8)));
typedef float    f32x4 __attribute__((ext_vector_type(4)));

// ---------------- workspace (bytes) ----------------
// xcv : [64][512][256] f16 = 16 MB (pre-converted x, single plane)
// rh  : [3][4][64][512] f16 = 1.5 MB (h ring, depth 4, single plane)
// bar : 4 groups x 64 arrival lines (64B each) + 4x4 flag lines
#define XCV_OFF 0UL
#define RH_OFF  16777216UL
#define BAR_OFF 18874368UL
#define BAR_BYTES 20480UL
#define WS_NEED (BAR_OFF + BAR_BYTES)

// LDS B-operand: hb[batch 16][oct 0..223][8 f16], row 225*16B = 3600 B
// (stride 900 dw = 4 mod 32: staging writes lane-contiguous conflict-free,
//  MFMA b128 reads 2-way = free)
#define H_ROW   1800              // f16 per batch row
#define HB_F16  (16 * H_ROW)      // 57600 B

__device__ __forceinline__ float sigf(float x) {
    return 1.f / (1.f + __expf(-x));
}
__device__ __forceinline__ float tanh_fast(float x) {
    x = fminf(fmaxf(x, -15.f), 15.f);
    const float e = __expf(2.f * x);
    return (e - 1.f) / (e + 1.f);
}
struct f16pair { _Float16 h, l; };
__device__ __forceinline__ f16pair cvt2(float x) {
    f16pair p;
    p.h = (_Float16)x;
    p.l = (_Float16)(x - (float)p.h);
    return p;
}
__device__ __forceinline__ uint32_t pack2(_Float16 a, _Float16 b) {
    union { _Float16 f[2]; uint32_t u; } U;
    U.f[0] = a; U.f[1] = b;
    return U.u;
}

// =====================================================================
// Prologue: x (f32) -> single f16 plane, once per call.
// =====================================================================
__global__ __launch_bounds__(256) void xcvt(
        const float* __restrict__ x, _Float16* __restrict__ xh, int n)
{
    const int stride = gridDim.x * 256;
    for (int i = blockIdx.x * 256 + threadIdx.x; i < n; i += stride)
        xh[i] = (_Float16)x[i];
}

// =====================================================================
// Persistent pipelined 3-layer LSTM.  grid = 256 WGs x 512 thr, 1 WG/CU.
// WG: g = bid&3 (16 batches), s = bid>>2 (8 units, all gates, all layers).
// Wave w<6: layer lw = w>>1, gate-pair gtile = w&1; 16 A-rows, full K in
// registers as f16 hi/lo frags (B single f16 -> 2 MFMAs per k-tile,
// 2 interleaved accumulators).  Cycle n: L0 t=n, L1 t=n-1, L2 t=n-2.
// Cycle: [x(n+1) load issued] h-stage -> sync -> MFMA -> sync ->
// pointwise + x(n+1) LDS write -> barrier (line-spread slots, master poll,
// replicated flags, acquire fence).
// =====================================================================
__global__ __launch_bounds__(512, 1) void lstm_mega(
        const _Float16* __restrict__ xh,
        const float* __restrict__ Wih0, const float* __restrict__ Whh0,
        const float* __restrict__ bih0, const float* __restrict__ bhh0,
        const float* __restrict__ Wih1, const float* __restrict__ Whh1,
        const float* __restrict__ bih1, const float* __restrict__ bhh1,
        const float* __restrict__ Wih2, const float* __restrict__ Whh2,
        const float* __restrict__ bih2, const float* __restrict__ bhh2,
        _Float16* __restrict__ rh,       // [3][4][64][512] f16
        uint32_t* __restrict__ bar)      // arr: g*1024+s*16 ; flags: 4096+g*64+r*16
{
    __shared__ _Float16 hb[HB_F16];         // 57600 B
    __shared__ float gates_t[3 * 32 * 17];  // [layer][gate*8+du][batch16]
    __shared__ float pad_force[6144];       // pad LDS > 80KB -> 1 WG/CU

    const int tid  = threadIdx.x;
    const int bid  = blockIdx.x;
    const int g    = bid & 3;
    const int s    = bid >> 2;            // 0..63
    if (bar == nullptr) pad_force[tid] = 0.f;   // keep pad alive (never true)
    uint32_t* arr  = bar + g * 1024;      // slot s at arr[s*16] (64B lines)
    uint32_t* flg  = bar + 4096 + g * 64; // 4 replicas, 16 dw apart

    const int wv   = tid >> 6;
    const int lane = tid & 63;
    const int m16  = lane & 15;
    const int quad = lane >> 4;

    // ---- A-fragments (waves 0-5): weight rows, f16 hi/lo, once at start
    f16x8 a_hi[32], a_lo[32];
    const int lw    = wv >> 1;
    const int gtile = wv & 1;
    const int nkt   = (lw == 0) ? 24 : 32;
    const int segN  = (lw == 0) ? 8 : 16;
    if (wv < 6) {
        const int gate = (gtile << 1) + (m16 >> 3);
        const int grow = gate * 512 + (s << 3) + (m16 & 7);
        const float* Wih = (lw == 0) ? Wih0 : ((lw == 1) ? Wih1 : Wih2);
        const float* Whh = (lw == 0) ? Whh0 : ((lw == 1) ? Whh1 : Whh2);
        const int Kin = (lw == 0) ? 256 : 512;
        const float* srcA = Wih + (size_t)grow * Kin;
        const float* srcB = Whh + (size_t)grow * 512;
        #pragma unroll
        for (int kt = 0; kt < 32; kt++) {
            if (kt < nkt) {
                const float* sp = (kt < segN) ? srcA + kt * 32 + (quad << 3)
                                              : srcB + (kt - segN) * 32 + (quad << 3);
                const float4 w0 = *(const float4*)sp;
                const float4 w1 = *(const float4*)(sp + 4);
                f16pair p;
                p = cvt2(w0.x); a_hi[kt][0] = p.h; a_lo[kt][0] = p.l;
                p = cvt2(w0.y); a_hi[kt][1] = p.h; a_lo[kt][1] = p.l;
                p = cvt2(w0.z); a_hi[kt][2] = p.h; a_lo[kt][2] = p.l;
                p = cvt2(w0.w); a_hi[kt][3] = p.h; a_lo[kt][3] = p.l;
                p = cvt2(w1.x); a_hi[kt][4] = p.h; a_lo[kt][4] = p.l;
                p = cvt2(w1.y); a_hi[kt][5] = p.h; a_lo[kt][5] = p.l;
                p = cvt2(w1.z); a_hi[kt][6] = p.h; a_lo[kt][6] = p.l;
                p = cvt2(w1.w); a_hi[kt][7] = p.h; a_lo[kt][7] = p.l;
            }
        }
    }
    const int lboctA = (lw == 0) ? 0  : ((lw == 1) ? 32 : 96);
    const int lboctB = (lw == 0) ? 32 : ((lw == 1) ? 96 : 160);

    // ---- pointwise mapping (tid<192): pl = tid>>6, 2 units/thread
    const int pl  = tid >> 6;
    const int pr  = tid & 63;
    const int du2 = pr & 3;
    const int b16 = pr >> 2;
    float bias_v[4][2];
    if (tid < 192) {
        const float* bi = (pl == 0) ? bih0 : ((pl == 1) ? bih1 : bih2);
        const float* bh = (pl == 0) ? bhh0 : ((pl == 1) ? bhh1 : bhh2);
        #pragma unroll
        for (int gate = 0; gate < 4; gate++)
            #pragma unroll
            for (int j = 0; j < 2; j++) {
                const int u = (s << 3) + (du2 << 1) + j;
                bias_v[gate][j] = bi[gate * 512 + u] + bh[gate * 512 + u];
            }
    }
    float c_reg[2] = {0.f, 0.f};

    // ---- staging mapping
    const int sb  = tid >> 5;             // 0..15 batch
    const int ol  = tid & 31;             // 0..31
    const int b64 = (g << 4) + sb;
    const int dx  = sb * H_ROW + (ol << 3);     // x oct LDS slot

    // prologue: stage x(0)
    {
        const size_t off = (((size_t)b64 * 512) << 8) + (ol << 3);
        *(f16x8*)&hb[dx] = *(const f16x8*)(xh + off);
    }

    for (int n = 0; n < 514; n++) {
        // ---- issue x(n+1) load early (barrier-independent)
        f16x8 xreg = {};
        if (n + 1 < 512) {
            const size_t off = (((size_t)b64 * 512 + (n + 1)) << 8) + (ol << 3);
            xreg = *(const f16x8*)(xh + off);
        }

        // ---- h-stage: h0[n-1], h1[n-2], h2[n-3] (single f16 copies)
        #pragma unroll
        for (int i = 0; i < 6; i++) {
            const int l    = i >> 1;
            const int octw = ol + ((i & 1) << 5);
            const int ts   = n - 1 - l;
            f16x8 v = {};
            if (ts >= 0 && ts < 512) {
                const size_t off = ((((size_t)l << 2) + (ts & 3)) * 64 + b64) * 512
                                 + ((size_t)octw << 3);
                v = *(const f16x8*)(rh + off);
            }
            *(f16x8*)&hb[sb * H_ROW + ((32 + (l << 6) + octw) << 3)] = v;
        }
        __syncthreads();

        // ---- MFMA (waves 0-5): 2 MFMAs/kt, 2 interleaved accumulators
        const int tl = n - lw;
        if (wv < 6 && tl >= 0 && tl < 512) {
            f32x4 acc0 = {0.f, 0.f, 0.f, 0.f};
            f32x4 acc1 = {0.f, 0.f, 0.f, 0.f};
            #pragma unroll
            for (int kt = 0; kt < 32; kt++) {
                if (kt < nkt) {
                    const int ob = ((kt < segN) ? lboctA + (kt << 2)
                                                : lboctB + ((kt - segN) << 2)) + quad;
                    const f16x8 b8 = *(const f16x8*)&hb[m16 * H_ROW + (ob << 3)];
                    if (kt & 1) {
                        acc1 = __builtin_amdgcn_mfma_f32_16x16x32_f16(a_hi[kt], b8, acc1, 0, 0, 0);
                        acc1 = __builtin_amdgcn_mfma_f32_16x16x32_f16(a_lo[kt], b8, acc1, 0, 0, 0);
                    } else {
                        acc0 = __builtin_amdgcn_mfma_f32_16x16x32_f16(a_hi[kt], b8, acc0, 0, 0, 0);
                        acc0 = __builtin_amdgcn_mfma_f32_16x16x32_f16(a_lo[kt], b8, acc0, 0, 0, 0);
                    }
                }
            }
            const f32x4 acc = acc0 + acc1;
            #pragma unroll
            for (int j = 0; j < 4; j++)
                gates_t[lw * 544 + ((gtile << 4) + (quad << 2) + j) * 17 + m16] = acc[j];
        }
        __syncthreads();

        // ---- x(n+1) LDS write (MFMA done; overlaps pointwise)
        if (n + 1 < 512)
            *(f16x8*)&hb[dx] = xreg;

        // ---- pointwise (waves 0-2, 2 units/thread), single-f16 h store
        const int tp = n - pl;
        if (tid < 192 && tp >= 0 && tp < 512) {
            _Float16 hv[2];
            #pragma unroll
            for (int j = 0; j < 2; j++) {
                const int du = (du2 << 1) + j;
                const float vi = gates_t[pl * 544 + (du) * 17 + b16]      + bias_v[0][j];
                const float vf = gates_t[pl * 544 + (8 + du) * 17 + b16]  + bias_v[1][j];
                const float vg = gates_t[pl * 544 + (16 + du) * 17 + b16] + bias_v[2][j];
                const float vo = gates_t[pl * 544 + (24 + du) * 17 + b16] + bias_v[3][j];
                const float gi = sigf(vi);
                const float gf = sigf(vf);
                const float gg = tanh_fast(vg);
                const float go = sigf(vo);
                const float c  = fmaf(gf, c_reg[j], gi * gg);
                c_reg[j] = c;
                hv[j] = (_Float16)(go * tanh_fast(c));
            }
            const size_t off = ((((size_t)pl << 2) + (tp & 3)) * 64 + (g << 4) + b16) * 512
                             + (s << 3) + (du2 << 1);
            __hip_atomic_store((uint32_t*)(rh + off), pack2(hv[0], hv[1]),
                               __ATOMIC_RELAXED, __HIP_MEMORY_SCOPE_AGENT);
        }

        // ---- group barrier (line-spread slots + replicated flags)
        if (n < 513) {
            __syncthreads();              // drain vmcnt: ring stores at LLC
            const uint32_t tgt = (uint32_t)(n + 1);
            if (tid == 0)
                __hip_atomic_store(&arr[s * 16], tgt, __ATOMIC_RELEASE,
                                   __HIP_MEMORY_SCOPE_AGENT);
            if (s == 0 && tid < 64) {     // master WG: lane l watches line l
                while (!__all((int)(__hip_atomic_load(&arr[lane * 16], __ATOMIC_RELAXED,
                                                      __HIP_MEMORY_SCOPE_AGENT) >= tgt)))
                    __builtin_amdgcn_s_sleep(1);
                if (tid == 0) {
                    #pragma unroll
                    for (int r = 0; r < 4; r++)
                        __hip_atomic_store(&flg[r * 16], tgt, __ATOMIC_RELEASE,
                                           __HIP_MEMORY_SCOPE_AGENT);
                }
            }
            if (tid == 0) {
                uint32_t* myflg = &flg[(s & 3) * 16];
                while (__hip_atomic_load(myflg, __ATOMIC_RELAXED,
                                         __HIP_MEMORY_SCOPE_AGENT) < tgt)
                    __builtin_amdgcn_s_sleep(1);
                __builtin_amdgcn_fence(__ATOMIC_ACQUIRE, "agent");
            }
            __syncthreads();
        }
    }
}

// =====================================================================
// FC head: out[b][c] = h2_final[b][:] . W_fc[c][:] + b_fc[c]
// =====================================================================
__global__ __launch_bounds__(256) void fc_head(
        const _Float16* __restrict__ rh,
        const float* __restrict__ Wfc, const float* __restrict__ bfc,
        float* __restrict__ out)           // [64][1000]
{
    __shared__ float hs[HDIM];
    const int b = blockIdx.x;
    const size_t off = ((size_t)(2 * 4 + 3) * 64 + b) * 512;   // h2[t=511], slot 3
    for (int i = threadIdx.x; i < HDIM; i += 256)
        hs[i] = (float)rh[off + i];
    __syncthreads();
    const int wave = threadIdx.x >> 6, lane = threadIdx.x & 63;
    for (int c = wave; c < NCLS; c += 4) {
        const float* wr = Wfc + (size_t)c * HDIM;
        float s = 0.f;
        for (int k = lane; k < HDIM; k += 64) s = fmaf(hs[k], wr[k], s);
        #pragma unroll
        for (int off2 = 32; off2 > 0; off2 >>= 1) s += __shfl_down(s, off2, 64);
        if (lane == 0) out[b * NCLS + c] = s + bfc[c];
    }
}

// =====================================================================
extern "C" void kernel_launch(void* const* d_in, const int* in_sizes, int n_in,
                              void* d_out, int out_size, void* d_ws, size_t ws_size,
                              hipStream_t stream)
{
    (void)in_sizes; (void)n_in; (void)out_size;
    if (ws_size < WS_NEED) return;   // readable failure instead of OOB fault

    const float* x    = (const float*)d_in[0];
    const float* Wih0 = (const float*)d_in[1];
    const float* Whh0 = (const float*)d_in[2];
    const float* bih0 = (const float*)d_in[3];
    const float* bhh0 = (const float*)d_in[4];
    const float* Wih1 = (const float*)d_in[5];
    const float* Whh1 = (const float*)d_in[6];
    const float* bih1 = (const float*)d_in[7];
    const float* bhh1 = (const float*)d_in[8];
    const float* Wih2 = (const float*)d_in[9];
    const float* Whh2 = (const float*)d_in[10];
    const float* bih2 = (const float*)d_in[11];
    const float* bhh2 = (const float*)d_in[12];
    const float* Wfc  = (const float*)d_in[13];
    const float* bfc  = (const float*)d_in[14];
    float* out = (float*)d_out;

    char* ws = (char*)d_ws;
    _Float16* xh  = (_Float16*)(ws + XCV_OFF);
    _Float16* rh  = (_Float16*)(ws + RH_OFF);
    uint32_t* bar = (uint32_t*)(ws + BAR_OFF);

    (void)hipMemsetAsync(bar, 0, BAR_BYTES, stream);
    xcvt<<<dim3(2048), dim3(256), 0, stream>>>(x, xh, 64 * 512 * 256);

    lstm_mega<<<dim3(256), dim3(512), 0, stream>>>(
        xh, Wih0, Whh0, bih0, bhh0, Wih1, Whh1, bih1, bhh1,
        Wih2, Whh2, bih2, bhh2, rh, bar);

    fc_head<<<dim3(64), dim3(256), 0, stream>>>(rh, Wfc, bfc, out);
}

// Round 11
// 7146.577 us; speedup vs baseline: 1.0267x; 1.0267x over previous
//
#include <hip/hip_runtime.h>
#include <stdint.h>

#define HDIM  512
#define NCLS  1000

typedef _Float16 f16x8 __attribute__((ext_vector_type(8)));
typedef float    f32x4 __attribute__((ext_vector_type(4)));

// ---------------- workspace (bytes) ----------------
// xcv : [64][512][256] f16 = 16 MB (pre-converted x, single plane)
// rh  : [3][4][64][512] f16 = 1.5 MB (h ring, depth 4, single plane)
// bar : packed — arr[g][64] dwords (4 lines/group) + flag line per group
#define XCV_OFF 0UL
#define RH_OFF  16777216UL
#define BAR_OFF 18874368UL
#define BAR_BYTES 4096UL
#define WS_NEED (BAR_OFF + BAR_BYTES)

// dynamic LDS pad: static 64128 B + 24576 B dyn = 89088 B > 80 KB -> 1 WG/CU
#define DYN_PAD 24576

// LDS B-operand: hb[batch 16][oct 0..223][8 f16], row 225*16B = 3600 B
// (stride 900 dw = 4 mod 32: staging writes lane-contiguous conflict-free,
//  MFMA b128 reads 2-way = free)
#define H_ROW   1800              // f16 per batch row
#define HB_F16  (16 * H_ROW)      // 57600 B

__device__ __forceinline__ float sigf(float x) {
    return 1.f / (1.f + __expf(-x));
}
__device__ __forceinline__ float tanh_fast(float x) {
    x = fminf(fmaxf(x, -15.f), 15.f);
    const float e = __expf(2.f * x);
    return (e - 1.f) / (e + 1.f);
}
struct f16pair { _Float16 h, l; };
__device__ __forceinline__ f16pair cvt2(float x) {
    f16pair p;
    p.h = (_Float16)x;
    p.l = (_Float16)(x - (float)p.h);
    return p;
}
__device__ __forceinline__ uint32_t pack2(_Float16 a, _Float16 b) {
    union { _Float16 f[2]; uint32_t u; } U;
    U.f[0] = a; U.f[1] = b;
    return U.u;
}

// =====================================================================
// Prologue: x (f32) -> single f16 plane, once per call.
// =====================================================================
__global__ __launch_bounds__(256) void xcvt(
        const float* __restrict__ x, _Float16* __restrict__ xh, int n)
{
    const int stride = gridDim.x * 256;
    for (int i = blockIdx.x * 256 + threadIdx.x; i < n; i += stride)
        xh[i] = (_Float16)x[i];
}

// =====================================================================
// Persistent pipelined 3-layer LSTM.  grid = 256 WGs x 512 thr, 1 WG/CU
// (89 KB LDS incl. launch-time dynamic pad).  WG: g = bid&3 (16 batches),
// s = bid>>2 (8 units).  Wave w<6: layer lw = w>>1, gate-pair gtile = w&1;
// 16 A-rows, full K in registers as f16 hi/lo frags (B single f16 ->
// 2 MFMAs/kt, 2 interleaved accumulators).  Cycle n: L0 t=n, L1 t=n-1,
// L2 t=n-2.  Cycle: [x(n+1) load issued] h-stage -> sync -> MFMA -> sync
// -> pointwise + x(n+1) LDS write -> barrier (packed 4-line arrivals,
// master poll, single flag/group, acquire fence).
// =====================================================================
__global__ __launch_bounds__(512, 1) void lstm_mega(
        const _Float16* __restrict__ xh,
        const float* __restrict__ Wih0, const float* __restrict__ Whh0,
        const float* __restrict__ bih0, const float* __restrict__ bhh0,
        const float* __restrict__ Wih1, const float* __restrict__ Whh1,
        const float* __restrict__ bih1, const float* __restrict__ bhh1,
        const float* __restrict__ Wih2, const float* __restrict__ Whh2,
        const float* __restrict__ bih2, const float* __restrict__ bhh2,
        _Float16* __restrict__ rh,       // [3][4][64][512] f16
        uint32_t* __restrict__ bar)      // arr[g][64] = bar[g*64+s]; flag[g] = bar[256+g*16]
{
    __shared__ _Float16 hb[HB_F16];         // 57600 B
    __shared__ float gates_t[3 * 32 * 17];  // [layer][gate*8+du][batch16]
    extern __shared__ char dynpad[];        // 24576 B launch-time pad (occupancy cap)

    const int tid  = threadIdx.x;
    const int bid  = blockIdx.x;
    const int g    = bid & 3;
    const int s    = bid >> 2;            // 0..63
    if (bid >= 16384) dynpad[0] = 1;      // opaque-false: keep pad referenced
    uint32_t* arr  = bar + g * 64;        // packed dword slots (4 lines)
    uint32_t* flg  = bar + 256 + g * 16;  // one flag line per group

    const int wv   = tid >> 6;
    const int lane = tid & 63;
    const int m16  = lane & 15;
    const int quad = lane >> 4;

    // ---- A-fragments (waves 0-5): weight rows, f16 hi/lo, once at start
    f16x8 a_hi[32], a_lo[32];
    const int lw    = wv >> 1;
    const int gtile = wv & 1;
    const int nkt   = (lw == 0) ? 24 : 32;
    const int segN  = (lw == 0) ? 8 : 16;
    if (wv < 6) {
        const int gate = (gtile << 1) + (m16 >> 3);
        const int grow = gate * 512 + (s << 3) + (m16 & 7);
        const float* Wih = (lw == 0) ? Wih0 : ((lw == 1) ? Wih1 : Wih2);
        const float* Whh = (lw == 0) ? Whh0 : ((lw == 1) ? Whh1 : Whh2);
        const int Kin = (lw == 0) ? 256 : 512;
        const float* srcA = Wih + (size_t)grow * Kin;
        const float* srcB = Whh + (size_t)grow * 512;
        #pragma unroll
        for (int kt = 0; kt < 32; kt++) {
            if (kt < nkt) {
                const float* sp = (kt < segN) ? srcA + kt * 32 + (quad << 3)
                                              : srcB + (kt - segN) * 32 + (quad << 3);
                const float4 w0 = *(const float4*)sp;
                const float4 w1 = *(const float4*)(sp + 4);
                f16pair p;
                p = cvt2(w0.x); a_hi[kt][0] = p.h; a_lo[kt][0] = p.l;
                p = cvt2(w0.y); a_hi[kt][1] = p.h; a_lo[kt][1] = p.l;
                p = cvt2(w0.z); a_hi[kt][2] = p.h; a_lo[kt][2] = p.l;
                p = cvt2(w0.w); a_hi[kt][3] = p.h; a_lo[kt][3] = p.l;
                p = cvt2(w1.x); a_hi[kt][4] = p.h; a_lo[kt][4] = p.l;
                p = cvt2(w1.y); a_hi[kt][5] = p.h; a_lo[kt][5] = p.l;
                p = cvt2(w1.z); a_hi[kt][6] = p.h; a_lo[kt][6] = p.l;
                p = cvt2(w1.w); a_hi[kt][7] = p.h; a_lo[kt][7] = p.l;
            }
        }
    }
    const int lboctA = (lw == 0) ? 0  : ((lw == 1) ? 32 : 96);
    const int lboctB = (lw == 0) ? 32 : ((lw == 1) ? 96 : 160);

    // ---- pointwise mapping (tid<192): pl = tid>>6, 2 units/thread
    const int pl  = tid >> 6;
    const int pr  = tid & 63;
    const int du2 = pr & 3;
    const int b16 = pr >> 2;
    float bias_v[4][2];
    if (tid < 192) {
        const float* bi = (pl == 0) ? bih0 : ((pl == 1) ? bih1 : bih2);
        const float* bh = (pl == 0) ? bhh0 : ((pl == 1) ? bhh1 : bhh2);
        #pragma unroll
        for (int gate = 0; gate < 4; gate++)
            #pragma unroll
            for (int j = 0; j < 2; j++) {
                const int u = (s << 3) + (du2 << 1) + j;
                bias_v[gate][j] = bi[gate * 512 + u] + bh[gate * 512 + u];
            }
    }
    float c_reg[2] = {0.f, 0.f};

    // ---- staging mapping
    const int sb  = tid >> 5;             // 0..15 batch
    const int ol  = tid & 31;             // 0..31
    const int b64 = (g << 4) + sb;
    const int dx  = sb * H_ROW + (ol << 3);     // x oct LDS slot

    // prologue: stage x(0)
    {
        const size_t off = (((size_t)b64 * 512) << 8) + (ol << 3);
        *(f16x8*)&hb[dx] = *(const f16x8*)(xh + off);
    }

    for (int n = 0; n < 514; n++) {
        // ---- issue x(n+1) load early (barrier-independent)
        f16x8 xreg = {};
        if (n + 1 < 512) {
            const size_t off = (((size_t)b64 * 512 + (n + 1)) << 8) + (ol << 3);
            xreg = *(const f16x8*)(xh + off);
        }

        // ---- h-stage: h0[n-1], h1[n-2], h2[n-3] (single f16 copies)
        #pragma unroll
        for (int i = 0; i < 6; i++) {
            const int l    = i >> 1;
            const int octw = ol + ((i & 1) << 5);
            const int ts   = n - 1 - l;
            f16x8 v = {};
            if (ts >= 0 && ts < 512) {
                const size_t off = ((((size_t)l << 2) + (ts & 3)) * 64 + b64) * 512
                                 + ((size_t)octw << 3);
                v = *(const f16x8*)(rh + off);
            }
            *(f16x8*)&hb[sb * H_ROW + ((32 + (l << 6) + octw) << 3)] = v;
        }
        __syncthreads();

        // ---- MFMA (waves 0-5): 2 MFMAs/kt, 2 interleaved accumulators
        const int tl = n - lw;
        if (wv < 6 && tl >= 0 && tl < 512) {
            f32x4 acc0 = {0.f, 0.f, 0.f, 0.f};
            f32x4 acc1 = {0.f, 0.f, 0.f, 0.f};
            #pragma unroll
            for (int kt = 0; kt < 32; kt++) {
                if (kt < nkt) {
                    const int ob = ((kt < segN) ? lboctA + (kt << 2)
                                                : lboctB + ((kt - segN) << 2)) + quad;
                    const f16x8 b8 = *(const f16x8*)&hb[m16 * H_ROW + (ob << 3)];
                    if (kt & 1) {
                        acc1 = __builtin_amdgcn_mfma_f32_16x16x32_f16(a_hi[kt], b8, acc1, 0, 0, 0);
                        acc1 = __builtin_amdgcn_mfma_f32_16x16x32_f16(a_lo[kt], b8, acc1, 0, 0, 0);
                    } else {
                        acc0 = __builtin_amdgcn_mfma_f32_16x16x32_f16(a_hi[kt], b8, acc0, 0, 0, 0);
                        acc0 = __builtin_amdgcn_mfma_f32_16x16x32_f16(a_lo[kt], b8, acc0, 0, 0, 0);
                    }
                }
            }
            const f32x4 acc = acc0 + acc1;
            #pragma unroll
            for (int j = 0; j < 4; j++)
                gates_t[lw * 544 + ((gtile << 4) + (quad << 2) + j) * 17 + m16] = acc[j];
        }
        __syncthreads();

        // ---- x(n+1) LDS write (MFMA done; overlaps pointwise)
        if (n + 1 < 512)
            *(f16x8*)&hb[dx] = xreg;

        // ---- pointwise (waves 0-2, 2 units/thread), single-f16 h store
        const int tp = n - pl;
        if (tid < 192 && tp >= 0 && tp < 512) {
            _Float16 hv[2];
            #pragma unroll
            for (int j = 0; j < 2; j++) {
                const int du = (du2 << 1) + j;
                const float vi = gates_t[pl * 544 + (du) * 17 + b16]      + bias_v[0][j];
                const float vf = gates_t[pl * 544 + (8 + du) * 17 + b16]  + bias_v[1][j];
                const float vg = gates_t[pl * 544 + (16 + du) * 17 + b16] + bias_v[2][j];
                const float vo = gates_t[pl * 544 + (24 + du) * 17 + b16] + bias_v[3][j];
                const float gi = sigf(vi);
                const float gf = sigf(vf);
                const float gg = tanh_fast(vg);
                const float go = sigf(vo);
                const float c  = fmaf(gf, c_reg[j], gi * gg);
                c_reg[j] = c;
                hv[j] = (_Float16)(go * tanh_fast(c));
            }
            const size_t off = ((((size_t)pl << 2) + (tp & 3)) * 64 + (g << 4) + b16) * 512
                             + (s << 3) + (du2 << 1);
            __hip_atomic_store((uint32_t*)(rh + off), pack2(hv[0], hv[1]),
                               __ATOMIC_RELAXED, __HIP_MEMORY_SCOPE_AGENT);
        }

        // ---- group barrier (packed arrivals, master poll, single flag)
        if (n < 513) {
            __syncthreads();              // drain vmcnt: ring stores at LLC
            const uint32_t tgt = (uint32_t)(n + 1);
            if (tid == 0)
                __hip_atomic_store(&arr[s], tgt, __ATOMIC_RELEASE,
                                   __HIP_MEMORY_SCOPE_AGENT);
            if (s == 0 && tid < 64) {     // master WG: 64-lane poll over 4 lines
                while (!__all((int)(__hip_atomic_load(&arr[lane], __ATOMIC_RELAXED,
                                                      __HIP_MEMORY_SCOPE_AGENT) >= tgt)))
                    __builtin_amdgcn_s_sleep(1);
                if (tid == 0)
                    __hip_atomic_store(flg, tgt, __ATOMIC_RELEASE,
                                       __HIP_MEMORY_SCOPE_AGENT);
            }
            if (tid == 0) {
                while (__hip_atomic_load(flg, __ATOMIC_RELAXED,
                                         __HIP_MEMORY_SCOPE_AGENT) < tgt)
                    __builtin_amdgcn_s_sleep(1);
                __builtin_amdgcn_fence(__ATOMIC_ACQUIRE, "agent");
            }
            __syncthreads();
        }
    }
}

// =====================================================================
// FC head: out[b][c] = h2_final[b][:] . W_fc[c][:] + b_fc[c]
// =====================================================================
__global__ __launch_bounds__(256) void fc_head(
        const _Float16* __restrict__ rh,
        const float* __restrict__ Wfc, const float* __restrict__ bfc,
        float* __restrict__ out)           // [64][1000]
{
    __shared__ float hs[HDIM];
    const int b = blockIdx.x;
    const size_t off = ((size_t)(2 * 4 + 3) * 64 + b) * 512;   // h2[t=511], slot 3
    for (int i = threadIdx.x; i < HDIM; i += 256)
        hs[i] = (float)rh[off + i];
    __syncthreads();
    const int wave = threadIdx.x >> 6, lane = threadIdx.x & 63;
    for (int c = wave; c < NCLS; c += 4) {
        const float* wr = Wfc + (size_t)c * HDIM;
        float s = 0.f;
        for (int k = lane; k < HDIM; k += 64) s = fmaf(hs[k], wr[k], s);
        #pragma unroll
        for (int off2 = 32; off2 > 0; off2 >>= 1) s += __shfl_down(s, off2, 64);
        if (lane == 0) out[b * NCLS + c] = s + bfc[c];
    }
}

// =====================================================================
extern "C" void kernel_launch(void* const* d_in, const int* in_sizes, int n_in,
                              void* d_out, int out_size, void* d_ws, size_t ws_size,
                              hipStream_t stream)
{
    (void)in_sizes; (void)n_in; (void)out_size;
    if (ws_size < WS_NEED) return;   // readable failure instead of OOB fault

    const float* x    = (const float*)d_in[0];
    const float* Wih0 = (const float*)d_in[1];
    const float* Whh0 = (const float*)d_in[2];
    const float* bih0 = (const float*)d_in[3];
    const float* bhh0 = (const float*)d_in[4];
    const float* Wih1 = (const float*)d_in[5];
    const float* Whh1 = (const float*)d_in[6];
    const float* bih1 = (const float*)d_in[7];
    const float* bhh1 = (const float*)d_in[8];
    const float* Wih2 = (const float*)d_in[9];
    const float* Whh2 = (const float*)d_in[10];
    const float* bih2 = (const float*)d_in[11];
    const float* bhh2 = (const float*)d_in[12];
    const float* Wfc  = (const float*)d_in[13];
    const float* bfc  = (const float*)d_in[14];
    float* out = (float*)d_out;

    char* ws = (char*)d_ws;
    _Float16* xh  = (_Float16*)(ws + XCV_OFF);
    _Float16* rh  = (_Float16*)(ws + RH_OFF);
    uint32_t* bar = (uint32_t*)(ws + BAR_OFF);

    (void)hipMemsetAsync(bar, 0, BAR_BYTES, stream);
    xcvt<<<dim3(2048), dim3(256), 0, stream>>>(x, xh, 64 * 512 * 256);

    lstm_mega<<<dim3(256), dim3(512), DYN_PAD, stream>>>(
        xh, Wih0, Whh0, bih0, bhh0, Wih1, Whh1, bih1, bhh1,
        Wih2, Whh2, bih2, bhh2, rh, bar);

    fc_head<<<dim3(64), dim3(256), 0, stream>>>(rh, Wfc, bfc, out);
}

// Round 12
// 6786.102 us; speedup vs baseline: 1.0812x; 1.0531x over previous
//
#include <hip/hip_runtime.h>
#include <stdint.h>

#define HDIM  512
#define NCLS  1000

typedef _Float16 f16x8 __attribute__((ext_vector_type(8)));
typedef float    f32x4 __attribute__((ext_vector_type(4)));

// ---------------- workspace (bytes) ----------------
// xcv : [64][512][256] f16 = 16 MB (pre-converted x, single plane)
// rh  : [3][4][64][512] f16 = 1.5 MB (h ring, depth 4, single plane)
// bar : arr[g][64] dwords packed (4 lines/group) + 4 flag-replica lines/group
#define XCV_OFF 0UL
#define RH_OFF  16777216UL
#define BAR_OFF 18874368UL
#define BAR_BYTES 4096UL
#define WS_NEED (BAR_OFF + BAR_BYTES)

// LDS B-operand: hb[batch 16][oct 0..223][8 f16], row 225*16B = 3600 B
// (stride 900 dw = 4 mod 32: staging writes lane-contiguous conflict-free,
//  MFMA b128 reads 2-way = free)
#define H_ROW   1800              // f16 per batch row
#define HB_F16  (16 * H_ROW)      // 57600 B

__device__ __forceinline__ float sigf(float x) {
    return 1.f / (1.f + __expf(-x));
}
__device__ __forceinline__ float tanh_fast(float x) {
    x = fminf(fmaxf(x, -15.f), 15.f);
    const float e = __expf(2.f * x);
    return (e - 1.f) / (e + 1.f);
}
struct f16pair { _Float16 h, l; };
__device__ __forceinline__ f16pair cvt2(float x) {
    f16pair p;
    p.h = (_Float16)x;
    p.l = (_Float16)(x - (float)p.h);
    return p;
}
__device__ __forceinline__ uint32_t pack2(_Float16 a, _Float16 b) {
    union { _Float16 f[2]; uint32_t u; } U;
    U.f[0] = a; U.f[1] = b;
    return U.u;
}

// =====================================================================
// Prologue: x (f32) -> single f16 plane, once per call.
// =====================================================================
__global__ __launch_bounds__(256) void xcvt(
        const float* __restrict__ x, _Float16* __restrict__ xh, int n)
{
    const int stride = gridDim.x * 256;
    for (int i = blockIdx.x * 256 + threadIdx.x; i < n; i += stride)
        xh[i] = (_Float16)x[i];
}

// =====================================================================
// Persistent pipelined 3-layer LSTM.  grid = 256 WGs x 512 thr.
// WG: g = bid&3 (16 batches; group occupies XCDs {g, g+4} by the %8
// dispatch swizzle), s = bid>>2 (8 units).  Wave w<6: layer lw = w>>1,
// gate-pair gtile = w&1; 16 A-rows, full K in registers as f16 hi/lo
// frags (B single f16 -> 2 MFMAs/kt, 2 interleaved accumulators).
// Cycle n: L0 t=n, L1 t=n-1, L2 t=n-2.  Cycle: stage x(n)+h's -> sync ->
// MFMA -> sync -> pointwise -> barrier (packed arrivals, throttled
// master poll, 4 flag replicas, throttled waiter poll, acquire fence).
// =====================================================================
__global__ __launch_bounds__(512, 1) void lstm_mega(
        const _Float16* __restrict__ xh,
        const float* __restrict__ Wih0, const float* __restrict__ Whh0,
        const float* __restrict__ bih0, const float* __restrict__ bhh0,
        const float* __restrict__ Wih1, const float* __restrict__ Whh1,
        const float* __restrict__ bih1, const float* __restrict__ bhh1,
        const float* __restrict__ Wih2, const float* __restrict__ Whh2,
        const float* __restrict__ bih2, const float* __restrict__ bhh2,
        _Float16* __restrict__ rh,       // [3][4][64][512] f16
        uint32_t* __restrict__ bar)      // arr[g][64]=bar[g*64+s]; flags bar[256+g*64+r*16]
{
    __shared__ _Float16 hb[HB_F16];         // 57600 B
    __shared__ float gates_t[3 * 32 * 17];  // [layer][gate*8+du][batch16]

    const int tid  = threadIdx.x;
    const int bid  = blockIdx.x;
    const int g    = bid & 3;
    const int s    = bid >> 2;            // 0..63
    uint32_t* arr  = bar + g * 64;        // packed dword slots (4 lines)
    uint32_t* flg  = bar + 256 + g * 64;  // 4 replica lines, 16 dw apart

    const int wv   = tid >> 6;
    const int lane = tid & 63;
    const int m16  = lane & 15;
    const int quad = lane >> 4;

    // ---- A-fragments (waves 0-5): weight rows, f16 hi/lo, once at start
    f16x8 a_hi[32], a_lo[32];
    const int lw    = wv >> 1;
    const int gtile = wv & 1;
    const int nkt   = (lw == 0) ? 24 : 32;
    const int segN  = (lw == 0) ? 8 : 16;
    if (wv < 6) {
        const int gate = (gtile << 1) + (m16 >> 3);
        const int grow = gate * 512 + (s << 3) + (m16 & 7);
        const float* Wih = (lw == 0) ? Wih0 : ((lw == 1) ? Wih1 : Wih2);
        const float* Whh = (lw == 0) ? Whh0 : ((lw == 1) ? Whh1 : Whh2);
        const int Kin = (lw == 0) ? 256 : 512;
        const float* srcA = Wih + (size_t)grow * Kin;
        const float* srcB = Whh + (size_t)grow * 512;
        #pragma unroll
        for (int kt = 0; kt < 32; kt++) {
            if (kt < nkt) {
                const float* sp = (kt < segN) ? srcA + kt * 32 + (quad << 3)
                                              : srcB + (kt - segN) * 32 + (quad << 3);
                const float4 w0 = *(const float4*)sp;
                const float4 w1 = *(const float4*)(sp + 4);
                f16pair p;
                p = cvt2(w0.x); a_hi[kt][0] = p.h; a_lo[kt][0] = p.l;
                p = cvt2(w0.y); a_hi[kt][1] = p.h; a_lo[kt][1] = p.l;
                p = cvt2(w0.z); a_hi[kt][2] = p.h; a_lo[kt][2] = p.l;
                p = cvt2(w0.w); a_hi[kt][3] = p.h; a_lo[kt][3] = p.l;
                p = cvt2(w1.x); a_hi[kt][4] = p.h; a_lo[kt][4] = p.l;
                p = cvt2(w1.y); a_hi[kt][5] = p.h; a_lo[kt][5] = p.l;
                p = cvt2(w1.z); a_hi[kt][6] = p.h; a_lo[kt][6] = p.l;
                p = cvt2(w1.w); a_hi[kt][7] = p.h; a_lo[kt][7] = p.l;
            }
        }
    }
    const int lboctA = (lw == 0) ? 0  : ((lw == 1) ? 32 : 96);
    const int lboctB = (lw == 0) ? 32 : ((lw == 1) ? 96 : 160);

    // ---- pointwise mapping (tid<192): pl = tid>>6, 2 units/thread
    const int pl  = tid >> 6;
    const int pr  = tid & 63;
    const int du2 = pr & 3;
    const int b16 = pr >> 2;
    float bias_v[4][2];
    if (tid < 192) {
        const float* bi = (pl == 0) ? bih0 : ((pl == 1) ? bih1 : bih2);
        const float* bh = (pl == 0) ? bhh0 : ((pl == 1) ? bhh1 : bhh2);
        #pragma unroll
        for (int gate = 0; gate < 4; gate++)
            #pragma unroll
            for (int j = 0; j < 2; j++) {
                const int u = (s << 3) + (du2 << 1) + j;
                bias_v[gate][j] = bi[gate * 512 + u] + bh[gate * 512 + u];
            }
    }
    float c_reg[2] = {0.f, 0.f};

    // ---- staging mapping
    const int sb  = tid >> 5;             // 0..15 batch
    const int ol  = tid & 31;             // 0..31
    const int b64 = (g << 4) + sb;
    const int dx  = sb * H_ROW + (ol << 3);     // x oct LDS slot

    for (int n = 0; n < 514; n++) {
        // ---- stage x(n) + h0[n-1], h1[n-2], h2[n-3] (single f16 copies)
        {
            f16x8 v = {};
            if (n < 512) {
                const size_t off = (((size_t)b64 * 512 + n) << 8) + (ol << 3);
                v = *(const f16x8*)(xh + off);
            }
            *(f16x8*)&hb[dx] = v;
        }
        #pragma unroll
        for (int i = 0; i < 6; i++) {
            const int l    = i >> 1;
            const int octw = ol + ((i & 1) << 5);
            const int ts   = n - 1 - l;
            f16x8 v = {};
            if (ts >= 0 && ts < 512) {
                const size_t off = ((((size_t)l << 2) + (ts & 3)) * 64 + b64) * 512
                                 + ((size_t)octw << 3);
                v = *(const f16x8*)(rh + off);
            }
            *(f16x8*)&hb[sb * H_ROW + ((32 + (l << 6) + octw) << 3)] = v;
        }
        __syncthreads();

        // ---- MFMA (waves 0-5): 2 MFMAs/kt, 2 interleaved accumulators
        const int tl = n - lw;
        if (wv < 6 && tl >= 0 && tl < 512) {
            f32x4 acc0 = {0.f, 0.f, 0.f, 0.f};
            f32x4 acc1 = {0.f, 0.f, 0.f, 0.f};
            #pragma unroll
            for (int kt = 0; kt < 32; kt++) {
                if (kt < nkt) {
                    const int ob = ((kt < segN) ? lboctA + (kt << 2)
                                                : lboctB + ((kt - segN) << 2)) + quad;
                    const f16x8 b8 = *(const f16x8*)&hb[m16 * H_ROW + (ob << 3)];
                    if (kt & 1) {
                        acc1 = __builtin_amdgcn_mfma_f32_16x16x32_f16(a_hi[kt], b8, acc1, 0, 0, 0);
                        acc1 = __builtin_amdgcn_mfma_f32_16x16x32_f16(a_lo[kt], b8, acc1, 0, 0, 0);
                    } else {
                        acc0 = __builtin_amdgcn_mfma_f32_16x16x32_f16(a_hi[kt], b8, acc0, 0, 0, 0);
                        acc0 = __builtin_amdgcn_mfma_f32_16x16x32_f16(a_lo[kt], b8, acc0, 0, 0, 0);
                    }
                }
            }
            const f32x4 acc = acc0 + acc1;
            #pragma unroll
            for (int j = 0; j < 4; j++)
                gates_t[lw * 544 + ((gtile << 4) + (quad << 2) + j) * 17 + m16] = acc[j];
        }
        __syncthreads();

        // ---- pointwise (waves 0-2, 2 units/thread), single-f16 h store
        const int tp = n - pl;
        if (tid < 192 && tp >= 0 && tp < 512) {
            _Float16 hv[2];
            #pragma unroll
            for (int j = 0; j < 2; j++) {
                const int du = (du2 << 1) + j;
                const float vi = gates_t[pl * 544 + (du) * 17 + b16]      + bias_v[0][j];
                const float vf = gates_t[pl * 544 + (8 + du) * 17 + b16]  + bias_v[1][j];
                const float vg = gates_t[pl * 544 + (16 + du) * 17 + b16] + bias_v[2][j];
                const float vo = gates_t[pl * 544 + (24 + du) * 17 + b16] + bias_v[3][j];
                const float gi = sigf(vi);
                const float gf = sigf(vf);
                const float gg = tanh_fast(vg);
                const float go = sigf(vo);
                const float c  = fmaf(gf, c_reg[j], gi * gg);
                c_reg[j] = c;
                hv[j] = (_Float16)(go * tanh_fast(c));
            }
            const size_t off = ((((size_t)pl << 2) + (tp & 3)) * 64 + (g << 4) + b16) * 512
                             + (s << 3) + (du2 << 1);
            __hip_atomic_store((uint32_t*)(rh + off), pack2(hv[0], hv[1]),
                               __ATOMIC_RELAXED, __HIP_MEMORY_SCOPE_AGENT);
        }

        // ---- group barrier (packed arrivals, throttled polls, flag replicas)
        if (n < 513) {
            __syncthreads();              // drain vmcnt: ring stores at LLC
            const uint32_t tgt = (uint32_t)(n + 1);
            if (tid == 0)
                __hip_atomic_store(&arr[s], tgt, __ATOMIC_RELEASE,
                                   __HIP_MEMORY_SCOPE_AGENT);
            if (s == 0 && tid < 64) {     // master WG: coalesced 64-lane poll
                while (!__all((int)(__hip_atomic_load(&arr[lane], __ATOMIC_RELAXED,
                                                      __HIP_MEMORY_SCOPE_AGENT) >= tgt)))
                    __builtin_amdgcn_s_sleep(2);
                if (tid == 0) {
                    #pragma unroll
                    for (int r = 0; r < 4; r++)
                        __hip_atomic_store(&flg[r * 16], tgt, __ATOMIC_RELEASE,
                                           __HIP_MEMORY_SCOPE_AGENT);
                }
            }
            if (tid == 0) {
                uint32_t* myflg = &flg[(s & 3) * 16];
                while (__hip_atomic_load(myflg, __ATOMIC_RELAXED,
                                         __HIP_MEMORY_SCOPE_AGENT) < tgt)
                    __builtin_amdgcn_s_sleep(4);
                __builtin_amdgcn_fence(__ATOMIC_ACQUIRE, "agent");
            }
            __syncthreads();
        }
    }
}

// =====================================================================
// FC head: out[b][c] = h2_final[b][:] . W_fc[c][:] + b_fc[c]
// =====================================================================
__global__ __launch_bounds__(256) void fc_head(
        const _Float16* __restrict__ rh,
        const float* __restrict__ Wfc, const float* __restrict__ bfc,
        float* __restrict__ out)           // [64][1000]
{
    __shared__ float hs[HDIM];
    const int b = blockIdx.x;
    const size_t off = ((size_t)(2 * 4 + 3) * 64 + b) * 512;   // h2[t=511], slot 3
    for (int i = threadIdx.x; i < HDIM; i += 256)
        hs[i] = (float)rh[off + i];
    __syncthreads();
    const int wave = threadIdx.x >> 6, lane = threadIdx.x & 63;
    for (int c = wave; c < NCLS; c += 4) {
        const float* wr = Wfc + (size_t)c * HDIM;
        float s = 0.f;
        for (int k = lane; k < HDIM; k += 64) s = fmaf(hs[k], wr[k], s);
        #pragma unroll
        for (int off2 = 32; off2 > 0; off2 >>= 1) s += __shfl_down(s, off2, 64);
        if (lane == 0) out[b * NCLS + c] = s + bfc[c];
    }
}

// =====================================================================
extern "C" void kernel_launch(void* const* d_in, const int* in_sizes, int n_in,
                              void* d_out, int out_size, void* d_ws, size_t ws_size,
                              hipStream_t stream)
{
    (void)in_sizes; (void)n_in; (void)out_size;
    if (ws_size < WS_NEED) return;   // readable failure instead of OOB fault

    const float* x    = (const float*)d_in[0];
    const float* Wih0 = (const float*)d_in[1];
    const float* Whh0 = (const float*)d_in[2];
    const float* bih0 = (const float*)d_in[3];
    const float* bhh0 = (const float*)d_in[4];
    const float* Wih1 = (const float*)d_in[5];
    const float* Whh1 = (const float*)d_in[6];
    const float* bih1 = (const float*)d_in[7];
    const float* bhh1 = (const float*)d_in[8];
    const float* Wih2 = (const float*)d_in[9];
    const float* Whh2 = (const float*)d_in[10];
    const float* bih2 = (const float*)d_in[11];
    const float* bhh2 = (const float*)d_in[12];
    const float* Wfc  = (const float*)d_in[13];
    const float* bfc  = (const float*)d_in[14];
    float* out = (float*)d_out;

    char* ws = (char*)d_ws;
    _Float16* xh  = (_Float16*)(ws + XCV_OFF);
    _Float16* rh  = (_Float16*)(ws + RH_OFF);
    uint32_t* bar = (uint32_t*)(ws + BAR_OFF);

    (void)hipMemsetAsync(bar, 0, BAR_BYTES, stream);
    xcvt<<<dim3(2048), dim3(256), 0, stream>>>(x, xh, 64 * 512 * 256);

    lstm_mega<<<dim3(256), dim3(512), 0, stream>>>(
        xh, Wih0, Whh0, bih0, bhh0, Wih1, Whh1, bih1, bhh1,
        Wih2, Whh2, bih2, bhh2, rh, bar);

    fc_head<<<dim3(64), dim3(256), 0, stream>>>(rh, Wfc, bfc, out);
}